// Round 1
// baseline (267.565 us; speedup 1.0000x reference)
//
#include <hip/hip_runtime.h>

#define NGRAPH 64

typedef _Float16 h4 __attribute__((ext_vector_type(4)));
typedef _Float16 h8 __attribute__((ext_vector_type(8)));
typedef float    f4 __attribute__((ext_vector_type(4)));
typedef float    f2 __attribute__((ext_vector_type(2)));

// ---- fused setup + histogram: blocks [0,nb_set) do setup; [nb_set,..) do hist ----
// deg must be zeroed before this kernel (hipMemsetAsync).
__global__ __launch_bounds__(256) void k_setup_hist(const int* __restrict__ bat,
                                                    const int* __restrict__ ei,
                                                    const float* __restrict__ W1,
                                                    const float* __restrict__ W2,
                                                    const float* __restrict__ W3,
                                                    _Float16* __restrict__ Wt,
                                                    int* __restrict__ deg,
                                                    int* __restrict__ rank,
                                                    int* __restrict__ gstart,
                                                    int N, int E, int nb_set) {
  int c = blockIdx.x;
  if (c < nb_set) {
    int i = c * 256 + threadIdx.x;
    if (i < 3 * 16384) {                    // Wt[l][n][k] = fp16(W_l[k][n])
      int l = i >> 14, j = i & 16383;
      int k = j >> 7, n = j & 127;
      const float* W = (l == 0) ? W1 : (l == 1) ? W2 : W3;
      Wt[l * 16384 + n * 128 + k] = (_Float16)W[k * 128 + n];
    }
    if (i < N) {
      int b = bat[i];
      int prev = (i == 0) ? -1 : bat[i - 1];
      for (int g = prev + 1; g <= b; ++g) gstart[g] = i;
      if (i == N - 1)
        for (int g = b + 1; g <= NGRAPH; ++g) gstart[g] = N;
    }
  } else {
    int e = (c - nb_set) * 256 + threadIdx.x;
    if (e < E) rank[e] = atomicAdd(&deg[ei[E + e]], 1);
  }
}

// ---- scan pass 1: per-block exclusive scan of deg ----
__global__ __launch_bounds__(256) void k_scan1(const int* __restrict__ deg,
                                               int* __restrict__ rowptr,
                                               int* __restrict__ bsum, int N) {
  __shared__ int s[256];
  int tid = threadIdx.x;
  int i = blockIdx.x * 256 + tid;
  int v = (i < N) ? deg[i] : 0;
  s[tid] = v;
  __syncthreads();
#pragma unroll
  for (int off = 1; off < 256; off <<= 1) {
    int t = (tid >= off) ? s[tid - off] : 0;
    __syncthreads();
    s[tid] += t;
    __syncthreads();
  }
  if (i < N) rowptr[i] = s[tid] - v;       // block-local exclusive
  if (tid == 255) bsum[blockIdx.x] = s[255];
}

// ---- scan pass 2+3 fused: each block redundantly reduces bsum[0..b); dinv ----
__global__ __launch_bounds__(256) void k_scan23(const int* __restrict__ deg,
                                                int* __restrict__ rowptr,
                                                const int* __restrict__ bsum,
                                                float* __restrict__ dinv,
                                                int N, int E) {
  __shared__ int red[256];
  int b = blockIdx.x, t = threadIdx.x;
  int partial = 0;
  for (int j = t; j < b; j += 256) partial += bsum[j];
  red[t] = partial;
  __syncthreads();
#pragma unroll
  for (int off = 128; off > 0; off >>= 1) {
    if (t < off) red[t] += red[t + off];
    __syncthreads();
  }
  int boff = red[0];
  int i = b * 256 + t;
  if (i < N) {
    rowptr[i] += boff;
    dinv[i] = rsqrtf((float)deg[i] + 1.0f);
  }
  if (i == 0) rowptr[N] = E;
}

// ---- fp8x16 accumulate helper: 16 fp8 bytes -> 16 fp32 accumulators ----
__device__ __forceinline__ void acc_u4(uint4 w, float* a) {
  f2 t;
  t = __builtin_amdgcn_cvt_pk_f32_fp8((int)w.x, false); a[0]  += t[0]; a[1]  += t[1];
  t = __builtin_amdgcn_cvt_pk_f32_fp8((int)w.x, true ); a[2]  += t[0]; a[3]  += t[1];
  t = __builtin_amdgcn_cvt_pk_f32_fp8((int)w.y, false); a[4]  += t[0]; a[5]  += t[1];
  t = __builtin_amdgcn_cvt_pk_f32_fp8((int)w.y, true ); a[6]  += t[0]; a[7]  += t[1];
  t = __builtin_amdgcn_cvt_pk_f32_fp8((int)w.z, false); a[8]  += t[0]; a[9]  += t[1];
  t = __builtin_amdgcn_cvt_pk_f32_fp8((int)w.z, true ); a[10] += t[0]; a[11] += t[1];
  t = __builtin_amdgcn_cvt_pk_f32_fp8((int)w.w, false); a[12] += t[0]; a[13] += t[1];
  t = __builtin_amdgcn_cvt_pk_f32_fp8((int)w.w, true ); a[14] += t[0]; a[15] += t[1];
}

// ---- stage W tile into LDS, XOR-swizzled (chunk ^ (row&7)), no barrier ----
__device__ __forceinline__ void stage_w_swz(const _Float16* __restrict__ Wt,
                                            _Float16* ws, int tid) {
#pragma unroll
  for (int i = 0; i < 8; ++i) {
    int c0 = tid + i * 256;
    int r = c0 >> 4;
    int c8 = c0 & 15;
    *(h8*)&ws[r * 128 + ((c8 ^ (r & 7)) << 3)] = *(const h8*)&Wt[r * 128 + (c8 << 3)];
  }
}

// ---- common MFMA compute+store given A-fragments (ws is swizzled) ----
__device__ __forceinline__ void mfma_compute_store(h8 af[2][4],
                                                   const _Float16* ws,
                                                   const float* __restrict__ dinv,
                                                   unsigned char* __restrict__ C,
                                                   int N, int rb, int lm, int q) {
  f4 acc[2][8];
#pragma unroll
  for (int mt = 0; mt < 2; ++mt)
#pragma unroll
    for (int ct = 0; ct < 8; ++ct)
      acc[mt][ct] = (f4){0.0f, 0.0f, 0.0f, 0.0f};

#pragma unroll
  for (int ct = 0; ct < 8; ++ct) {
    const int rr = ct * 16 + lm, r7 = rr & 7;
    h8 bf[4];
#pragma unroll
    for (int kc = 0; kc < 4; ++kc)
      bf[kc] = *(const h8*)&ws[rr * 128 + (((kc * 4 + q) ^ r7) << 3)];
#pragma unroll
    for (int mt = 0; mt < 2; ++mt)
#pragma unroll
      for (int kc = 0; kc < 4; ++kc)
        acc[mt][ct] = __builtin_amdgcn_mfma_f32_16x16x32_f16(af[mt][kc], bf[kc],
                                                             acc[mt][ct], 0, 0, 0);
  }

#pragma unroll
  for (int mt = 0; mt < 2; ++mt) {
#pragma unroll
    for (int r = 0; r < 4; ++r) {
      int row = rb + mt * 16 + q * 4 + r;
      if (row < N) {
        float dn = dinv[row];
        unsigned char* Cp = &C[(size_t)row * 128 + lm];
#pragma unroll
        for (int ct = 0; ct < 8; ++ct) {
          float v = acc[mt][ct][r] * dn;
          unsigned int p = __builtin_amdgcn_cvt_pk_fp8_f32(v, v, 0, false);
          Cp[ct * 16] = (unsigned char)(p & 0xFF);
        }
      }
    }
  }
}

// ---- fused: blocks [0,nbg) do mfma layer-1 (fp32 A = x); rest do CSR fill ----
__global__ __launch_bounds__(256) void k_fill_mfma(const float* __restrict__ A32,
                                                   const _Float16* __restrict__ Wt,
                                                   const float* __restrict__ dinv,
                                                   unsigned char* __restrict__ C,
                                                   const int* __restrict__ ei,
                                                   const int* __restrict__ rowptr,
                                                   const int* __restrict__ rank,
                                                   int* __restrict__ col,
                                                   int N, int E, int nbg) {
  __shared__ _Float16 ws[128 * 128];
  const int tid = threadIdx.x;
  if ((int)blockIdx.x < nbg) {
    stage_w_swz(Wt, ws, tid);
    __syncthreads();
    const int wv = tid >> 6, l = tid & 63;
    const int lm = l & 15, q = l >> 4;
    const int rb = blockIdx.x * 128 + wv * 32;

    h8 af[2][4];
#pragma unroll
    for (int mt = 0; mt < 2; ++mt) {
      int row = rb + mt * 16 + lm;
      if (row < N) {
        const float* Ap = &A32[(size_t)row * 128];
#pragma unroll
        for (int kc = 0; kc < 4; ++kc) {
          float4 v0 = *(const float4*)&Ap[kc * 32 + q * 8];
          float4 v1 = *(const float4*)&Ap[kc * 32 + q * 8 + 4];
          h8 a;
          a[0] = (_Float16)v0.x; a[1] = (_Float16)v0.y;
          a[2] = (_Float16)v0.z; a[3] = (_Float16)v0.w;
          a[4] = (_Float16)v1.x; a[5] = (_Float16)v1.y;
          a[6] = (_Float16)v1.z; a[7] = (_Float16)v1.w;
          af[mt][kc] = a;
        }
      } else {
#pragma unroll
        for (int kc = 0; kc < 4; ++kc) {
          h8 a;
#pragma unroll
          for (int j = 0; j < 8; ++j) a[j] = (_Float16)0.0f;
          af[mt][kc] = a;
        }
      }
    }
    mfma_compute_store(af, ws, dinv, C, N, rb, lm, q);
  } else {
    int e = (blockIdx.x - nbg) * 256 + tid;
    if (e < E) {
      int d = ei[E + e];
      col[rowptr[d] + rank[e]] = ei[e];
    }
  }
}

// ---- fused gather + GEMM for layers 2,3:
// per block: gather 128 nodes' aggregated h (relu(dinv*(agg+self)+b)) into LDS,
// one barrier, then MFMA h @ W_next -> fp8 table (dinv-scaled) for the next layer.
// Gather: 8 lanes/node (uint4 = 16B/lane), 32 node-groups/block, 4 serial tiles.
__global__ __launch_bounds__(256) void k_fused(const unsigned char* __restrict__ Tin,
                                               const _Float16* __restrict__ Wt,
                                               const int* __restrict__ rowptr,
                                               const int* __restrict__ col,
                                               const float* __restrict__ dinv,
                                               const float* __restrict__ bias,
                                               unsigned char* __restrict__ Tout,
                                               int N) {
  __shared__ _Float16 ws[128 * 128];
  __shared__ _Float16 hs[128 * 128];
  const int tid = threadIdx.x, bid = blockIdx.x;

  stage_w_swz(Wt, ws, tid);          // no barrier yet; ws only read after sync

  const int grp = tid >> 3, sl = tid & 7;
  const uint4* xw = (const uint4*)Tin;     // row = 8 uint4 (128 B)
#pragma unroll 1
  for (int it = 0; it < 4; ++it) {
    int local = it * 32 + grp;
    int node = bid * 128 + local;
    float a[16];
#pragma unroll
    for (int j = 0; j < 16; ++j) a[j] = 0.0f;
    float dn = 1.0f;
    if (node < N) {
      int beg = rowptr[node], end = rowptr[node + 1];
      int e = beg;
      for (; e + 3 < end; e += 4) {
        int s0 = col[e], s1 = col[e + 1], s2 = col[e + 2], s3 = col[e + 3];
        uint4 w0 = xw[(size_t)s0 * 8 + sl];
        uint4 w1 = xw[(size_t)s1 * 8 + sl];
        uint4 w2 = xw[(size_t)s2 * 8 + sl];
        uint4 w3 = xw[(size_t)s3 * 8 + sl];
        acc_u4(w0, a); acc_u4(w1, a); acc_u4(w2, a); acc_u4(w3, a);
      }
      for (; e < end; ++e) acc_u4(xw[(size_t)col[e] * 8 + sl], a);
      acc_u4(xw[(size_t)node * 8 + sl], a);      // self-loop term
      dn = dinv[node];
    }
    const float* bp = &bias[sl * 16];
    float4 b0 = *(const float4*)&bp[0];
    float4 b1 = *(const float4*)&bp[4];
    float4 b2 = *(const float4*)&bp[8];
    float4 b3 = *(const float4*)&bp[12];
    h8 o0, o1;
    o0[0] = (_Float16)fmaxf(fmaf(dn, a[0],  b0.x), 0.0f);
    o0[1] = (_Float16)fmaxf(fmaf(dn, a[1],  b0.y), 0.0f);
    o0[2] = (_Float16)fmaxf(fmaf(dn, a[2],  b0.z), 0.0f);
    o0[3] = (_Float16)fmaxf(fmaf(dn, a[3],  b0.w), 0.0f);
    o0[4] = (_Float16)fmaxf(fmaf(dn, a[4],  b1.x), 0.0f);
    o0[5] = (_Float16)fmaxf(fmaf(dn, a[5],  b1.y), 0.0f);
    o0[6] = (_Float16)fmaxf(fmaf(dn, a[6],  b1.z), 0.0f);
    o0[7] = (_Float16)fmaxf(fmaf(dn, a[7],  b1.w), 0.0f);
    o1[0] = (_Float16)fmaxf(fmaf(dn, a[8],  b2.x), 0.0f);
    o1[1] = (_Float16)fmaxf(fmaf(dn, a[9],  b2.y), 0.0f);
    o1[2] = (_Float16)fmaxf(fmaf(dn, a[10], b2.z), 0.0f);
    o1[3] = (_Float16)fmaxf(fmaf(dn, a[11], b2.w), 0.0f);
    o1[4] = (_Float16)fmaxf(fmaf(dn, a[12], b3.x), 0.0f);
    o1[5] = (_Float16)fmaxf(fmaf(dn, a[13], b3.y), 0.0f);
    o1[6] = (_Float16)fmaxf(fmaf(dn, a[14], b3.z), 0.0f);
    o1[7] = (_Float16)fmaxf(fmaf(dn, a[15], b3.w), 0.0f);
    int r7 = local & 7;
    *(h8*)&hs[local * 128 + (((2 * sl)     ^ r7) << 3)] = o0;
    *(h8*)&hs[local * 128 + (((2 * sl + 1) ^ r7) << 3)] = o1;
  }
  __syncthreads();

  // MFMA phase: A fragments from swizzled hs
  const int wv = tid >> 6, l = tid & 63;
  const int lm = l & 15, q = l >> 4;
  h8 af[2][4];
#pragma unroll
  for (int mt = 0; mt < 2; ++mt) {
    int r = wv * 32 + mt * 16 + lm, r7 = r & 7;
#pragma unroll
    for (int kc = 0; kc < 4; ++kc)
      af[mt][kc] = *(const h8*)&hs[r * 128 + (((kc * 4 + q) ^ r7) << 3)];
  }
  mfma_compute_store(af, ws, dinv, Tout, N, bid * 128 + wv * 32, lm, q);
}

// ---- final gather (fp8 table -> fp16 h): h[n] = relu(dinv[n]*(xws[n]+sum xws[src])+b)
// 16 lanes per node, lane owns 8 cols (8B uint2 loads); 16 nodes/block.
__global__ __launch_bounds__(256) void k_gather(const int* __restrict__ rowptr,
                                                const int* __restrict__ col,
                                                const unsigned char* __restrict__ xf8,
                                                const float* __restrict__ dinv,
                                                const float* __restrict__ b,
                                                _Float16* __restrict__ h, int N) {
  int node = blockIdx.x * 16 + (threadIdx.x >> 4);
  if (node >= N) return;
  int sl = threadIdx.x & 15;               // lane within node group
  int beg = rowptr[node], end = rowptr[node + 1];
  const uint2* xw = (const uint2*)xf8;     // row stride 16 uint2

  float a0 = 0, a1 = 0, a2 = 0, a3 = 0, a4 = 0, a5 = 0, a6 = 0, a7 = 0;
  int e = beg;
  for (; e + 3 < end; e += 4) {
    int s0 = col[e], s1 = col[e + 1], s2 = col[e + 2], s3 = col[e + 3];
    uint2 w0 = xw[(size_t)s0 * 16 + sl];
    uint2 w1 = xw[(size_t)s1 * 16 + sl];
    uint2 w2 = xw[(size_t)s2 * 16 + sl];
    uint2 w3 = xw[(size_t)s3 * 16 + sl];
#pragma unroll
    for (int j = 0; j < 4; ++j) {
      uint2 w = (j == 0) ? w0 : (j == 1) ? w1 : (j == 2) ? w2 : w3;
      f2 lx = __builtin_amdgcn_cvt_pk_f32_fp8((int)w.x, false);
      f2 hx = __builtin_amdgcn_cvt_pk_f32_fp8((int)w.x, true);
      f2 ly = __builtin_amdgcn_cvt_pk_f32_fp8((int)w.y, false);
      f2 hy = __builtin_amdgcn_cvt_pk_f32_fp8((int)w.y, true);
      a0 += lx[0]; a1 += lx[1]; a2 += hx[0]; a3 += hx[1];
      a4 += ly[0]; a5 += ly[1]; a6 += hy[0]; a7 += hy[1];
    }
  }
  for (; e < end; ++e) {
    uint2 w = xw[(size_t)col[e] * 16 + sl];
    f2 lx = __builtin_amdgcn_cvt_pk_f32_fp8((int)w.x, false);
    f2 hx = __builtin_amdgcn_cvt_pk_f32_fp8((int)w.x, true);
    f2 ly = __builtin_amdgcn_cvt_pk_f32_fp8((int)w.y, false);
    f2 hy = __builtin_amdgcn_cvt_pk_f32_fp8((int)w.y, true);
    a0 += lx[0]; a1 += lx[1]; a2 += hx[0]; a3 += hx[1];
    a4 += ly[0]; a5 += ly[1]; a6 += hy[0]; a7 += hy[1];
  }
  float dn = dinv[node];
  uint2 wsf = xw[(size_t)node * 16 + sl];
  f2 slx = __builtin_amdgcn_cvt_pk_f32_fp8((int)wsf.x, false);
  f2 shx = __builtin_amdgcn_cvt_pk_f32_fp8((int)wsf.x, true);
  f2 sly = __builtin_amdgcn_cvt_pk_f32_fp8((int)wsf.y, false);
  f2 shy = __builtin_amdgcn_cvt_pk_f32_fp8((int)wsf.y, true);
  int c = sl * 8;
  float4 b0 = *(const float4*)&b[c];
  float4 b1v = *(const float4*)&b[c + 4];
  h8 o;
  o[0] = (_Float16)fmaxf(fmaf(dn, a0 + slx[0], b0.x), 0.0f);
  o[1] = (_Float16)fmaxf(fmaf(dn, a1 + slx[1], b0.y), 0.0f);
  o[2] = (_Float16)fmaxf(fmaf(dn, a2 + shx[0], b0.z), 0.0f);
  o[3] = (_Float16)fmaxf(fmaf(dn, a3 + shx[1], b0.w), 0.0f);
  o[4] = (_Float16)fmaxf(fmaf(dn, a4 + sly[0], b1v.x), 0.0f);
  o[5] = (_Float16)fmaxf(fmaf(dn, a5 + sly[1], b1v.y), 0.0f);
  o[6] = (_Float16)fmaxf(fmaf(dn, a6 + shy[0], b1v.z), 0.0f);
  o[7] = (_Float16)fmaxf(fmaf(dn, a7 + shy[1], b1v.w), 0.0f);
  *(h8*)&h[(size_t)node * 128 + c] = o;
}

// ---- fused pool + head: one block per graph, no atomics ----
__global__ __launch_bounds__(256) void k_poolhead(const _Float16* __restrict__ h,
                                                  const int* __restrict__ gstart,
                                                  const float* __restrict__ Wc,
                                                  const float* __restrict__ bc,
                                                  float* __restrict__ out) {
  int g = blockIdx.x;
  int beg = gstart[g], end = gstart[g + 1];
  int tid = threadIdx.x;
  int ty = tid >> 5;            // 8 row groups
  int q = (tid & 31) * 4;       // col quad

  float4 acc; acc.x = acc.y = acc.z = acc.w = 0.0f;
  for (int r = beg + ty; r < end; r += 8) {
    h4 v = *(const h4*)&h[(size_t)r * 128 + q];
    acc.x += (float)v[0]; acc.y += (float)v[1];
    acc.z += (float)v[2]; acc.w += (float)v[3];
  }
  __shared__ float s[8][128];
  *(float4*)&s[ty][q] = acc;
  __syncthreads();
  if (tid < 32) {
    int qq = tid * 4;
    float4 t; t.x = t.y = t.z = t.w = 0.0f;
#pragma unroll
    for (int j = 0; j < 8; ++j) {
      float4 v = *(float4*)&s[j][qq];
      t.x += v.x; t.y += v.y; t.z += v.z; t.w += v.w;
    }
    *(float4*)&s[0][qq] = t;
  }
  __syncthreads();
  if (tid < 10) {
    float cntf = (float)(end - beg);
    float inv = 1.0f / fmaxf(cntf, 1.0f);
    float a = 0.0f;
    for (int hh = 0; hh < 128; ++hh)
      a = fmaf(s[0][hh], Wc[hh * 10 + tid], a);
    out[g * 10 + tid] = a * inv + bc[tid];
  }
}

extern "C" void kernel_launch(void* const* d_in, const int* in_sizes, int n_in,
                              void* d_out, int out_size, void* d_ws, size_t ws_size,
                              hipStream_t stream) {
  const float* x   = (const float*)d_in[0];
  const int*   ei  = (const int*)d_in[1];
  const int*   bat = (const int*)d_in[2];
  const float* W1  = (const float*)d_in[3];
  const float* b1  = (const float*)d_in[4];
  const float* W2  = (const float*)d_in[5];
  const float* b2  = (const float*)d_in[6];
  const float* W3  = (const float*)d_in[7];
  const float* b3  = (const float*)d_in[8];
  const float* Wc  = (const float*)d_in[9];
  const float* bc  = (const float*)d_in[10];

  const int N = in_sizes[0] / 128;
  const int E = in_sizes[1] / 2;
  const int NP = ((N + 127) / 128) * 128;        // padded rows

  // workspace layout
  char* wsb = (char*)d_ws;
  int*   deg    = (int*)wsb;                      wsb += (size_t)N * 4;
  int*   rowptr = (int*)wsb;                      wsb += (size_t)(N + 1) * 4;
  int*   bsum   = (int*)wsb;                      wsb += 256 * 4;
  float* dinv   = (float*)wsb;                    wsb += (size_t)N * 4;
  int*   col    = (int*)wsb;                      wsb += (size_t)E * 4;
  int*   rank   = (int*)wsb;                      wsb += (size_t)E * 4;
  int*   gstart = (int*)wsb;                      wsb += (NGRAPH + 1) * 4;
  wsb = (char*)(((size_t)wsb + 255) & ~(size_t)255);
  _Float16* Wt  = (_Float16*)wsb;                 wsb += 3 * 16384 * 2;
  wsb = (char*)(((size_t)wsb + 255) & ~(size_t)255);
  unsigned char* B1a = (unsigned char*)wsb;       wsb += (size_t)NP * 128;     // fp8 table A
  wsb = (char*)(((size_t)wsb + 255) & ~(size_t)255);
  unsigned char* B1b = (unsigned char*)wsb;       wsb += (size_t)NP * 128;     // fp8 table B
  wsb = (char*)(((size_t)wsb + 255) & ~(size_t)255);
  _Float16* B2  = (_Float16*)wsb;                                              // fp16 h (final)

  const int setup_elems = (N > 3 * 16384) ? N : 3 * 16384;
  const int nb_set = (setup_elems + 255) / 256;
  const int nb_N   = (N + 255) / 256;
  const int nb_E   = (E + 255) / 256;
  const int nb_gem = (N + 127) / 128;
  const int nb_gat = (N + 15) / 16;

  hipMemsetAsync(deg, 0, (size_t)N * 4, stream);
  k_setup_hist<<<nb_set + nb_E, 256, 0, stream>>>(bat, ei, W1, W2, W3,
                                                  Wt, deg, rank, gstart,
                                                  N, E, nb_set);
  k_scan1<<<nb_N, 256, 0, stream>>>(deg, rowptr, bsum, N);
  k_scan23<<<nb_N, 256, 0, stream>>>(deg, rowptr, bsum, dinv, N, E);

  // layer 1 GEMM (fp32 A = x, in-register cvt) overlapped with atomic-free CSR fill
  k_fill_mfma<<<nb_gem + nb_E, 256, 0, stream>>>(x, Wt, dinv, B1a,
                                                 ei, rowptr, rank, col, N, E, nb_gem);
  // layers 2,3: fused gather (into LDS) + GEMM, ping-pong fp8 tables
  k_fused<<<nb_gem, 256, 0, stream>>>(B1a, Wt + 16384, rowptr, col, dinv, b1, B1b, N);
  k_fused<<<nb_gem, 256, 0, stream>>>(B1b, Wt + 32768, rowptr, col, dinv, b2, B1a, N);
  // final layer: gather to fp16 h, then pool+head
  k_gather<<<nb_gat, 256, 0, stream>>>(rowptr, col, B1a, dinv, b3, B2, N);
  k_poolhead<<<NGRAPH, 256, 0, stream>>>(B2, gstart, Wc, bc, (float*)d_out);
}